// Round 1
// baseline (715.962 us; speedup 1.0000x reference)
//
#include <hip/hip_runtime.h>
#include <math.h>

// SpatialTransformerBlock on MI355X (gfx950).
// Round 1: correctness-first full pipeline, bf16 MFMA GEMMs (m93-level structure),
// flash-style fused attention, fp32 residual stream kept in d_out.

typedef __attribute__((ext_vector_type(8))) short short8;   // 8 bf16 (4 VGPR) MFMA frag
typedef __attribute__((ext_vector_type(4))) float f32x4;    // MFMA accum
typedef unsigned short u16;

#define DEVI __device__ __forceinline__

static constexpr int Bb = 16, Nn = 1024, Dd = 384;
static constexpr int Mm = Bb * Nn;            // 16384 token rows
static constexpr int H1 = 6, HD1 = 64, H2 = 3, HD2 = 128, MLPH = 1536;

DEVI float bf2f(u16 u) { return __uint_as_float(((unsigned int)u) << 16); }
DEVI u16 f2bf(float f) {                       // round-nearest-even
    unsigned int x = __float_as_uint(f);
    return (u16)((x + 0x7fffu + ((x >> 16) & 1u)) >> 16);
}
DEVI f32x4 mfma16(short8 a, short8 b, f32x4 c) {
    return __builtin_amdgcn_mfma_f32_16x16x32_bf16(a, b, c, 0, 0, 0);
}

// ---------------- fp32 -> bf16 weight conversion ----------------
__global__ void cvt_kernel(const float* __restrict__ src, u16* __restrict__ dst, int n) {
    int i = blockIdx.x * 256 + threadIdx.x;
    if (i < n) dst[i] = f2bf(src[i]);
}

// ---------------- LayerNorm: 1 wave per 384-elem row ----------------
// out_bf16 = LN(x)*g+b ; optionally copy x (fp32) to xcopy (residual stream init).
__global__ __launch_bounds__(256) void ln_kernel(
    const float* __restrict__ x, const float* __restrict__ g, const float* __restrict__ b,
    u16* __restrict__ out, float* __restrict__ xcopy)
{
    int wave = threadIdx.x >> 6, lane = threadIdx.x & 63;
    int row = blockIdx.x * 4 + wave;
    const float* xr = x + (size_t)row * Dd;
    float v[6], s = 0.f, sq = 0.f;
#pragma unroll
    for (int e = 0; e < 6; ++e) { v[e] = xr[e * 64 + lane]; s += v[e]; }
#pragma unroll
    for (int e = 0; e < 6; ++e) sq += v[e] * v[e];
#pragma unroll
    for (int m = 1; m < 64; m <<= 1) { s += __shfl_xor(s, m, 64); sq += __shfl_xor(sq, m, 64); }
    float mean = s * (1.f / 384.f);
    float var  = sq * (1.f / 384.f) - mean * mean;
    float rs   = rsqrtf(var + 1e-5f);
#pragma unroll
    for (int e = 0; e < 6; ++e) {
        int c = e * 64 + lane;
        out[(size_t)row * Dd + c] = f2bf((v[e] - mean) * rs * g[c] + b[c]);
        if (xcopy) xcopy[(size_t)row * Dd + c] = v[e];
    }
}

// ---------------- GEMM: C = A[M,K](bf16) @ W[wrow0+N, K](bf16)^T + bias ----------------
// 128x128 tile, 4 waves, each wave a 64x64 quadrant of 4x4 16x16x32 MFMAs, BK=32.
// EPI: 0 = bias -> bf16 ; 1 = bias + exact GELU -> bf16 ; 2 = resid + alpha*(acc+bias) -> f32
template<int EPI>
__global__ __launch_bounds__(256) void gemm_bt(
    const u16* __restrict__ A, int lda,
    const u16* __restrict__ W, int ldw, int wrow0,
    const float* __restrict__ bias, int brow0, int K,
    void* __restrict__ Cout, int ldc,
    const float* __restrict__ resid, float alpha)
{
    __shared__ __align__(16) u16 As[128][32];
    __shared__ __align__(16) u16 Bs[128][32];
    const int m0 = blockIdx.x * 128, n0 = blockIdx.y * 128;
    const int tid = threadIdx.x, wv = tid >> 6, lane = tid & 63;
    const int wr = wv >> 1, wc = wv & 1;
    const int rsel = lane & 15, ksel = (lane >> 4) * 8;

    f32x4 acc[4][4];
#pragma unroll
    for (int i = 0; i < 4; ++i)
#pragma unroll
        for (int j = 0; j < 4; ++j) acc[i][j] = f32x4{0.f, 0.f, 0.f, 0.f};

    for (int kb = 0; kb < K; kb += 32) {
        __syncthreads();
#pragma unroll
        for (int cc = 0; cc < 2; ++cc) {
            int c = tid + cc * 256;             // 512 16B chunks per 128x32 tile
            int r = c >> 2, cb = (c & 3) * 8;
            *(uint4*)&As[r][cb] = *(const uint4*)&A[(size_t)(m0 + r) * lda + kb + cb];
            *(uint4*)&Bs[r][cb] = *(const uint4*)&W[(size_t)(wrow0 + n0 + r) * ldw + kb + cb];
        }
        __syncthreads();
        short8 af[4], bfr[4];
#pragma unroll
        for (int i = 0; i < 4; ++i) af[i]  = *(const short8*)&As[wr * 64 + i * 16 + rsel][ksel];
#pragma unroll
        for (int j = 0; j < 4; ++j) bfr[j] = *(const short8*)&Bs[wc * 64 + j * 16 + rsel][ksel];
#pragma unroll
        for (int i = 0; i < 4; ++i)
#pragma unroll
            for (int j = 0; j < 4; ++j) acc[i][j] = mfma16(af[i], bfr[j], acc[i][j]);
    }

    const int rgrp = (lane >> 4) * 4, cidx = lane & 15;
#pragma unroll
    for (int i = 0; i < 4; ++i) {
#pragma unroll
        for (int j = 0; j < 4; ++j) {
            int n = n0 + wc * 64 + j * 16 + cidx;
            float bval = bias[brow0 + n];
#pragma unroll
            for (int r = 0; r < 4; ++r) {
                int m = m0 + wr * 64 + i * 16 + rgrp + r;
                float v = acc[i][j][r] + bval;
                if constexpr (EPI == 0) {
                    ((u16*)Cout)[(size_t)m * ldc + n] = f2bf(v);
                } else if constexpr (EPI == 1) {
                    float gg = 0.5f * v * (1.f + erff(v * 0.70710678118654752f));
                    ((u16*)Cout)[(size_t)m * ldc + n] = f2bf(gg);
                } else {
                    ((float*)Cout)[(size_t)m * ldc + n] =
                        resid[(size_t)m * ldc + n] + alpha * v;
                }
            }
        }
    }
}

// ---------------- fused attention (flash-style, online softmax) ----------------
// Block: 4 waves, 64 Q-rows (16 per wave). Iterate 16 KV tiles of 64.
// Output written as bf16 into O[M, 384] at head offset h*HD.
template<int HD>
__global__ __launch_bounds__(256) void attn_kernel(
    const u16* __restrict__ Qb, int qs,
    const u16* __restrict__ Kb, int ks,
    const u16* __restrict__ Vb, int vs,
    u16* __restrict__ Ob, float scale)
{
    constexpr int CH = HD / 8;                  // uint4 chunks per row
    __shared__ __align__(16) u16 Qs[64][HD];
    __shared__ __align__(16) u16 Ks[64][HD];
    __shared__ __align__(16) u16 Vt[HD][64];    // V transposed: [channel][kv]
    __shared__ __align__(16) u16 Ps[4][16][64]; // per-wave P strip

    const int q0 = blockIdx.x * 64, h = blockIdx.y, b = blockIdx.z;
    const int tid = threadIdx.x, wv = tid >> 6, lane = tid & 63;
    const int rsel = lane & 15, kgrp = lane >> 4;

    for (int c = tid; c < 64 * CH; c += 256) {
        int r = c / CH, cb = (c % CH) * 8;
        *(uint4*)&Qs[r][cb] = *(const uint4*)&Qb[(size_t)(b * Nn + q0 + r) * qs + h * HD + cb];
    }

    float mrow[4], lrow[4];
    f32x4 oacc[HD / 16];
#pragma unroll
    for (int r = 0; r < 4; ++r) { mrow[r] = -INFINITY; lrow[r] = 0.f; }
#pragma unroll
    for (int ct = 0; ct < HD / 16; ++ct) oacc[ct] = f32x4{0.f, 0.f, 0.f, 0.f};

    for (int t = 0; t < Nn / 64; ++t) {
        int kv0 = t * 64;
        __syncthreads();                        // prev-iter LDS reads done
        for (int c = tid; c < 64 * CH; c += 256) {
            int r = c / CH, cb = (c % CH) * 8;
            *(uint4*)&Ks[r][cb] = *(const uint4*)&Kb[(size_t)(b * Nn + kv0 + r) * ks + h * HD + cb];
            uint4 vvv = *(const uint4*)&Vb[(size_t)(b * Nn + kv0 + r) * vs + h * HD + cb];
            const u16* e = (const u16*)&vvv;
#pragma unroll
            for (int j = 0; j < 8; ++j) Vt[cb + j][r] = e[j];
        }
        __syncthreads();

        // S = Q K^T  (wave's 16-row strip x 64 kv)
        f32x4 sacc[4];
#pragma unroll
        for (int ct = 0; ct < 4; ++ct) sacc[ct] = f32x4{0.f, 0.f, 0.f, 0.f};
#pragma unroll
        for (int kk = 0; kk < HD / 32; ++kk) {
            short8 aq = *(const short8*)&Qs[wv * 16 + rsel][kk * 32 + kgrp * 8];
#pragma unroll
            for (int ct = 0; ct < 4; ++ct) {
                short8 bk = *(const short8*)&Ks[ct * 16 + rsel][kk * 32 + kgrp * 8];
                sacc[ct] = mfma16(aq, bk, sacc[ct]);
            }
        }
        // online softmax; D layout: row = 4*kgrp+r, col = ct*16+rsel
#pragma unroll
        for (int r = 0; r < 4; ++r) {
            float s0 = sacc[0][r] * scale, s1 = sacc[1][r] * scale;
            float s2 = sacc[2][r] * scale, s3 = sacc[3][r] * scale;
            float mx = fmaxf(fmaxf(s0, s1), fmaxf(s2, s3));
#pragma unroll
            for (int mk = 1; mk < 16; mk <<= 1) mx = fmaxf(mx, __shfl_xor(mx, mk, 64));
            float mnew = fmaxf(mrow[r], mx);
            float al = expf(mrow[r] - mnew);
            float p0 = expf(s0 - mnew), p1 = expf(s1 - mnew);
            float p2 = expf(s2 - mnew), p3 = expf(s3 - mnew);
            float rsum = p0 + p1 + p2 + p3;
#pragma unroll
            for (int mk = 1; mk < 16; mk <<= 1) rsum += __shfl_xor(rsum, mk, 64);
            lrow[r] = lrow[r] * al + rsum;
            mrow[r] = mnew;
#pragma unroll
            for (int ct = 0; ct < HD / 16; ++ct) oacc[ct][r] *= al;
            Ps[wv][kgrp * 4 + r][rsel]      = f2bf(p0);
            Ps[wv][kgrp * 4 + r][16 + rsel] = f2bf(p1);
            Ps[wv][kgrp * 4 + r][32 + rsel] = f2bf(p2);
            Ps[wv][kgrp * 4 + r][48 + rsel] = f2bf(p3);
        }
        __syncthreads();                        // P visible (and V staged)

        // O += P V
#pragma unroll
        for (int kk = 0; kk < 2; ++kk) {
            short8 ap = *(const short8*)&Ps[wv][rsel][kk * 32 + kgrp * 8];
#pragma unroll
            for (int ct = 0; ct < HD / 16; ++ct) {
                short8 bv = *(const short8*)&Vt[ct * 16 + rsel][kk * 32 + kgrp * 8];
                oacc[ct] = mfma16(ap, bv, oacc[ct]);
            }
        }
    }

#pragma unroll
    for (int r = 0; r < 4; ++r) {
        float inv = 1.f / lrow[r];
        size_t m = (size_t)(b * Nn + q0 + wv * 16 + kgrp * 4 + r);
#pragma unroll
        for (int ct = 0; ct < HD / 16; ++ct)
            Ob[m * Dd + h * HD + ct * 16 + rsel] = f2bf(oacc[ct][r] * inv);
    }
}

// ---------------- 3x3 weighted stencil on the 32x32 grid ----------------
__global__ __launch_bounds__(256) void stencil_kernel(
    const u16* __restrict__ xs, u16* __restrict__ nb)
{
    int tid = blockIdx.x * 256 + threadIdx.x;   // Mm*48 threads, 8 channels each
    if (tid >= Mm * 48) return;
    int c8 = tid % 48, pos = tid / 48;
    int j = pos & 31, i = (pos >> 5) & 31;
    float acc[8] = {0, 0, 0, 0, 0, 0, 0, 0};
    float wsum = 0.f;
#pragma unroll
    for (int di = -1; di <= 1; ++di) {
#pragma unroll
        for (int dj = -1; dj <= 1; ++dj) {
            int ii = i + di, jj = j + dj;
            if (ii < 0 || ii > 31 || jj < 0 || jj > 31) continue;
            float w = (di != 0 && dj != 0) ? 0.5f : 1.0f;
            uint4 vv = *(const uint4*)&xs[((size_t)pos + (size_t)(di * 32 + dj)) * Dd + c8 * 8];
            const u16* e = (const u16*)&vv;
#pragma unroll
            for (int q = 0; q < 8; ++q) acc[q] += w * bf2f(e[q]);
            wsum += w;
        }
    }
    float invw = 1.f / wsum;
    u16 ov[8];
#pragma unroll
    for (int q = 0; q < 8; ++q) ov[q] = f2bf(acc[q] * invw);
    *(uint4*)&nb[(size_t)pos * Dd + c8 * 8] = *(const uint4*)ov;
}

// ---------------- driver ----------------
extern "C" void kernel_launch(void* const* d_in, const int* in_sizes, int n_in,
                              void* d_out, int out_size, void* d_ws, size_t ws_size,
                              hipStream_t stream) {
    const float* x        = (const float*)d_in[0];
    const float* ln1_g    = (const float*)d_in[1];
    const float* ln1_b    = (const float*)d_in[2];
    const float* attn_wi  = (const float*)d_in[3];
    const float* attn_bi  = (const float*)d_in[4];
    const float* attn_wo  = (const float*)d_in[5];
    const float* attn_bo  = (const float*)d_in[6];
    const float* sln_g    = (const float*)d_in[7];
    const float* sln_b    = (const float*)d_in[8];
    const float* sattn_wi = (const float*)d_in[9];
    const float* sattn_bi = (const float*)d_in[10];
    const float* sattn_wo = (const float*)d_in[11];
    const float* sattn_bo = (const float*)d_in[12];
    const float* ln2_g    = (const float*)d_in[13];
    const float* ln2_b    = (const float*)d_in[14];
    const float* mlp_w1   = (const float*)d_in[15];
    const float* mlp_b1   = (const float*)d_in[16];
    const float* mlp_w2   = (const float*)d_in[17];
    const float* mlp_b2   = (const float*)d_in[18];
    float* out = (float*)d_out;

    char* base = (char*)d_ws;
    size_t off = 0;
    auto take = [&](size_t bytes) -> char* {
        char* p = base + off; off += (bytes + 255) & ~(size_t)255; return p;
    };
    u16* wbi1  = (u16*)take((size_t)1152 * 384 * 2);
    u16* wbo1  = (u16*)take((size_t)384 * 384 * 2);
    u16* wbi2  = (u16*)take((size_t)1152 * 384 * 2);
    u16* wbo2  = (u16*)take((size_t)384 * 384 * 2);
    u16* wbm1  = (u16*)take((size_t)MLPH * 384 * 2);
    u16* wbm2  = (u16*)take((size_t)384 * MLPH * 2);
    u16* bufA  = (u16*)take((size_t)Mm * Dd * 2);            // xn / xs / ln2
    u16* bufB  = (u16*)take((size_t)Mm * 1536 * 2);          // qkv1 | q2,kv2,nb | mlp hidden
    u16* bufO  = (u16*)take((size_t)Mm * Dd * 2);            // attention outputs
    u16* qkv1 = bufB;
    u16* q2   = bufB;
    u16* kv2  = bufB + (size_t)Mm * 384;
    u16* nbuf = bufB + (size_t)Mm * 1152;
    (void)ws_size; (void)in_sizes; (void)n_in; (void)out_size;

    // weights -> bf16
    cvt_kernel<<<(1152 * 384 + 255) / 256, 256, 0, stream>>>(attn_wi, wbi1, 1152 * 384);
    cvt_kernel<<<(384 * 384 + 255) / 256, 256, 0, stream>>>(attn_wo, wbo1, 384 * 384);
    cvt_kernel<<<(1152 * 384 + 255) / 256, 256, 0, stream>>>(sattn_wi, wbi2, 1152 * 384);
    cvt_kernel<<<(384 * 384 + 255) / 256, 256, 0, stream>>>(sattn_wo, wbo2, 384 * 384);
    cvt_kernel<<<(MLPH * 384 + 255) / 256, 256, 0, stream>>>(mlp_w1, wbm1, MLPH * 384);
    cvt_kernel<<<(384 * MLPH + 255) / 256, 256, 0, stream>>>(mlp_w2, wbm2, 384 * MLPH);

    // block 1: x = x + MHA(LN(x))
    ln_kernel<<<Mm / 4, 256, 0, stream>>>(x, ln1_g, ln1_b, bufA, out);
    gemm_bt<0><<<dim3(Mm / 128, 1152 / 128), 256, 0, stream>>>(
        bufA, Dd, wbi1, Dd, 0, attn_bi, 0, Dd, qkv1, 1152, nullptr, 1.f);
    attn_kernel<64><<<dim3(Nn / 64, H1, Bb), 256, 0, stream>>>(
        qkv1, 1152, qkv1 + Dd, 1152, qkv1 + 2 * Dd, 1152, bufO, 0.125f);
    gemm_bt<2><<<dim3(Mm / 128, Dd / 128), 256, 0, stream>>>(
        bufO, Dd, wbo1, Dd, 0, attn_bo, 0, Dd, out, Dd, out, 1.f);

    // block 2: x = x + 0.5 * MHA(xs, nb, nb)
    ln_kernel<<<Mm / 4, 256, 0, stream>>>(out, sln_g, sln_b, bufA, nullptr);
    stencil_kernel<<<(Mm * 48) / 256, 256, 0, stream>>>(bufA, nbuf);
    gemm_bt<0><<<dim3(Mm / 128, Dd / 128), 256, 0, stream>>>(
        bufA, Dd, wbi2, Dd, 0, sattn_bi, 0, Dd, q2, Dd, nullptr, 1.f);
    gemm_bt<0><<<dim3(Mm / 128, 768 / 128), 256, 0, stream>>>(
        nbuf, Dd, wbi2, Dd, 384, sattn_bi, 384, Dd, kv2, 768, nullptr, 1.f);
    attn_kernel<128><<<dim3(Nn / 64, H2, Bb), 256, 0, stream>>>(
        q2, Dd, kv2, 768, kv2 + Dd, 768, bufO, 0.088388347648318447f);
    gemm_bt<2><<<dim3(Mm / 128, Dd / 128), 256, 0, stream>>>(
        bufO, Dd, wbo2, Dd, 0, sattn_bo, 0, Dd, out, Dd, out, 0.5f);

    // MLP: x = x + W2 gelu(W1 LN(x))
    ln_kernel<<<Mm / 4, 256, 0, stream>>>(out, ln2_g, ln2_b, bufA, nullptr);
    gemm_bt<1><<<dim3(Mm / 128, MLPH / 128), 256, 0, stream>>>(
        bufA, Dd, wbm1, Dd, 0, mlp_b1, 0, Dd, bufB, MLPH, nullptr, 1.f);
    gemm_bt<2><<<dim3(Mm / 128, Dd / 128), 256, 0, stream>>>(
        bufB, MLPH, wbm2, MLPH, 0, mlp_b2, 0, MLPH, out, Dd, out, 1.f);
}

// Round 2
// 620.669 us; speedup vs baseline: 1.1535x; 1.1535x over previous
//
#include <hip/hip_runtime.h>
#include <math.h>

// SpatialTransformerBlock on MI355X (gfx950).
// Round 2: +16B row padding on ALL LDS tiles (attention was 16-way bank-conflicted:
// 8.7e7 conflict cycles = ~60% of attn time), __expf in softmax.

typedef __attribute__((ext_vector_type(8))) short short8;   // 8 bf16 (4 VGPR) MFMA frag
typedef __attribute__((ext_vector_type(4))) float f32x4;    // MFMA accum
typedef unsigned short u16;

#define DEVI __device__ __forceinline__

static constexpr int Bb = 16, Nn = 1024, Dd = 384;
static constexpr int Mm = Bb * Nn;            // 16384 token rows
static constexpr int H1 = 6, HD1 = 64, H2 = 3, HD2 = 128, MLPH = 1536;

DEVI float bf2f(u16 u) { return __uint_as_float(((unsigned int)u) << 16); }
DEVI u16 f2bf(float f) {                       // round-nearest-even
    unsigned int x = __float_as_uint(f);
    return (u16)((x + 0x7fffu + ((x >> 16) & 1u)) >> 16);
}
DEVI f32x4 mfma16(short8 a, short8 b, f32x4 c) {
    return __builtin_amdgcn_mfma_f32_16x16x32_bf16(a, b, c, 0, 0, 0);
}

// ---------------- fp32 -> bf16 weight conversion ----------------
__global__ void cvt_kernel(const float* __restrict__ src, u16* __restrict__ dst, int n) {
    int i = blockIdx.x * 256 + threadIdx.x;
    if (i < n) dst[i] = f2bf(src[i]);
}

// ---------------- LayerNorm: 1 wave per 384-elem row ----------------
__global__ __launch_bounds__(256) void ln_kernel(
    const float* __restrict__ x, const float* __restrict__ g, const float* __restrict__ b,
    u16* __restrict__ out, float* __restrict__ xcopy)
{
    int wave = threadIdx.x >> 6, lane = threadIdx.x & 63;
    int row = blockIdx.x * 4 + wave;
    const float* xr = x + (size_t)row * Dd;
    float v[6], s = 0.f, sq = 0.f;
#pragma unroll
    for (int e = 0; e < 6; ++e) { v[e] = xr[e * 64 + lane]; s += v[e]; }
#pragma unroll
    for (int e = 0; e < 6; ++e) sq += v[e] * v[e];
#pragma unroll
    for (int m = 1; m < 64; m <<= 1) { s += __shfl_xor(s, m, 64); sq += __shfl_xor(sq, m, 64); }
    float mean = s * (1.f / 384.f);
    float var  = sq * (1.f / 384.f) - mean * mean;
    float rs   = rsqrtf(var + 1e-5f);
#pragma unroll
    for (int e = 0; e < 6; ++e) {
        int c = e * 64 + lane;
        out[(size_t)row * Dd + c] = f2bf((v[e] - mean) * rs * g[c] + b[c]);
        if (xcopy) xcopy[(size_t)row * Dd + c] = v[e];
    }
}

// ---------------- GEMM: C = A[M,K](bf16) @ W[wrow0+N, K](bf16)^T + bias ----------------
// 128x128 tile, 4 waves, 4x4 16x16x32 MFMAs per wave, BK=32. LDS rows padded +8 bf16.
template<int EPI>
__global__ __launch_bounds__(256) void gemm_bt(
    const u16* __restrict__ A, int lda,
    const u16* __restrict__ W, int ldw, int wrow0,
    const float* __restrict__ bias, int brow0, int K,
    void* __restrict__ Cout, int ldc,
    const float* __restrict__ resid, float alpha)
{
    __shared__ __align__(16) u16 As[128][40];   // stride 80B = 20 banks (conflict-free)
    __shared__ __align__(16) u16 Bs[128][40];
    const int m0 = blockIdx.x * 128, n0 = blockIdx.y * 128;
    const int tid = threadIdx.x, wv = tid >> 6, lane = tid & 63;
    const int wr = wv >> 1, wc = wv & 1;
    const int rsel = lane & 15, ksel = (lane >> 4) * 8;

    f32x4 acc[4][4];
#pragma unroll
    for (int i = 0; i < 4; ++i)
#pragma unroll
        for (int j = 0; j < 4; ++j) acc[i][j] = f32x4{0.f, 0.f, 0.f, 0.f};

    for (int kb = 0; kb < K; kb += 32) {
        __syncthreads();
#pragma unroll
        for (int cc = 0; cc < 2; ++cc) {
            int c = tid + cc * 256;             // 512 16B chunks per 128x32 tile
            int r = c >> 2, cb = (c & 3) * 8;
            *(uint4*)&As[r][cb] = *(const uint4*)&A[(size_t)(m0 + r) * lda + kb + cb];
            *(uint4*)&Bs[r][cb] = *(const uint4*)&W[(size_t)(wrow0 + n0 + r) * ldw + kb + cb];
        }
        __syncthreads();
        short8 af[4], bfr[4];
#pragma unroll
        for (int i = 0; i < 4; ++i) af[i]  = *(const short8*)&As[wr * 64 + i * 16 + rsel][ksel];
#pragma unroll
        for (int j = 0; j < 4; ++j) bfr[j] = *(const short8*)&Bs[wc * 64 + j * 16 + rsel][ksel];
#pragma unroll
        for (int i = 0; i < 4; ++i)
#pragma unroll
            for (int j = 0; j < 4; ++j) acc[i][j] = mfma16(af[i], bfr[j], acc[i][j]);
    }

    const int rgrp = (lane >> 4) * 4, cidx = lane & 15;
#pragma unroll
    for (int i = 0; i < 4; ++i) {
#pragma unroll
        for (int j = 0; j < 4; ++j) {
            int n = n0 + wc * 64 + j * 16 + cidx;
            float bval = bias[brow0 + n];
#pragma unroll
            for (int r = 0; r < 4; ++r) {
                int m = m0 + wr * 64 + i * 16 + rgrp + r;
                float v = acc[i][j][r] + bval;
                if constexpr (EPI == 0) {
                    ((u16*)Cout)[(size_t)m * ldc + n] = f2bf(v);
                } else if constexpr (EPI == 1) {
                    float gg = 0.5f * v * (1.f + erff(v * 0.70710678118654752f));
                    ((u16*)Cout)[(size_t)m * ldc + n] = f2bf(gg);
                } else {
                    ((float*)Cout)[(size_t)m * ldc + n] =
                        resid[(size_t)m * ldc + n] + alpha * v;
                }
            }
        }
    }
}

// ---------------- fused attention (flash-style, online softmax) ----------------
// Block: 4 waves, 64 Q-rows (16 per wave). 16 KV tiles of 64. LDS rows padded +8 bf16.
template<int HD>
__global__ __launch_bounds__(256) void attn_kernel(
    const u16* __restrict__ Qb, int qs,
    const u16* __restrict__ Kb, int ks,
    const u16* __restrict__ Vb, int vs,
    u16* __restrict__ Ob, float scale)
{
    constexpr int CH = HD / 8;                  // uint4 chunks per row
    __shared__ __align__(16) u16 Qs[64][HD + 8];
    __shared__ __align__(16) u16 Ks[64][HD + 8];
    __shared__ __align__(16) u16 Vt[HD][72];    // V transposed: [channel][kv]
    __shared__ __align__(16) u16 Ps[4][16][72]; // per-wave P strip

    const int q0 = blockIdx.x * 64, h = blockIdx.y, b = blockIdx.z;
    const int tid = threadIdx.x, wv = tid >> 6, lane = tid & 63;
    const int rsel = lane & 15, kgrp = lane >> 4;

    for (int c = tid; c < 64 * CH; c += 256) {
        int r = c / CH, cb = (c % CH) * 8;
        *(uint4*)&Qs[r][cb] = *(const uint4*)&Qb[(size_t)(b * Nn + q0 + r) * qs + h * HD + cb];
    }

    float mrow[4], lrow[4];
    f32x4 oacc[HD / 16];
#pragma unroll
    for (int r = 0; r < 4; ++r) { mrow[r] = -INFINITY; lrow[r] = 0.f; }
#pragma unroll
    for (int ct = 0; ct < HD / 16; ++ct) oacc[ct] = f32x4{0.f, 0.f, 0.f, 0.f};

    for (int t = 0; t < Nn / 64; ++t) {
        int kv0 = t * 64;
        __syncthreads();                        // prev-iter LDS reads done
        for (int c = tid; c < 64 * CH; c += 256) {
            int r = c / CH, cb = (c % CH) * 8;
            *(uint4*)&Ks[r][cb] = *(const uint4*)&Kb[(size_t)(b * Nn + kv0 + r) * ks + h * HD + cb];
            uint4 vvv = *(const uint4*)&Vb[(size_t)(b * Nn + kv0 + r) * vs + h * HD + cb];
            const u16* e = (const u16*)&vvv;
#pragma unroll
            for (int j = 0; j < 8; ++j) Vt[cb + j][r] = e[j];
        }
        __syncthreads();

        // S = Q K^T  (wave's 16-row strip x 64 kv)
        f32x4 sacc[4];
#pragma unroll
        for (int ct = 0; ct < 4; ++ct) sacc[ct] = f32x4{0.f, 0.f, 0.f, 0.f};
#pragma unroll
        for (int kk = 0; kk < HD / 32; ++kk) {
            short8 aq = *(const short8*)&Qs[wv * 16 + rsel][kk * 32 + kgrp * 8];
#pragma unroll
            for (int ct = 0; ct < 4; ++ct) {
                short8 bk = *(const short8*)&Ks[ct * 16 + rsel][kk * 32 + kgrp * 8];
                sacc[ct] = mfma16(aq, bk, sacc[ct]);
            }
        }
        // online softmax; D layout: row = 4*kgrp+r, col = ct*16+rsel
#pragma unroll
        for (int r = 0; r < 4; ++r) {
            float s0 = sacc[0][r] * scale, s1 = sacc[1][r] * scale;
            float s2 = sacc[2][r] * scale, s3 = sacc[3][r] * scale;
            float mx = fmaxf(fmaxf(s0, s1), fmaxf(s2, s3));
#pragma unroll
            for (int mk = 1; mk < 16; mk <<= 1) mx = fmaxf(mx, __shfl_xor(mx, mk, 64));
            float mnew = fmaxf(mrow[r], mx);
            float al = __expf(mrow[r] - mnew);
            float p0 = __expf(s0 - mnew), p1 = __expf(s1 - mnew);
            float p2 = __expf(s2 - mnew), p3 = __expf(s3 - mnew);
            float rsum = p0 + p1 + p2 + p3;
#pragma unroll
            for (int mk = 1; mk < 16; mk <<= 1) rsum += __shfl_xor(rsum, mk, 64);
            lrow[r] = lrow[r] * al + rsum;
            mrow[r] = mnew;
#pragma unroll
            for (int ct = 0; ct < HD / 16; ++ct) oacc[ct][r] *= al;
            Ps[wv][kgrp * 4 + r][rsel]      = f2bf(p0);
            Ps[wv][kgrp * 4 + r][16 + rsel] = f2bf(p1);
            Ps[wv][kgrp * 4 + r][32 + rsel] = f2bf(p2);
            Ps[wv][kgrp * 4 + r][48 + rsel] = f2bf(p3);
        }
        __syncthreads();                        // P visible (and V staged)

        // O += P V
#pragma unroll
        for (int kk = 0; kk < 2; ++kk) {
            short8 ap = *(const short8*)&Ps[wv][rsel][kk * 32 + kgrp * 8];
#pragma unroll
            for (int ct = 0; ct < HD / 16; ++ct) {
                short8 bv = *(const short8*)&Vt[ct * 16 + rsel][kk * 32 + kgrp * 8];
                oacc[ct] = mfma16(ap, bv, oacc[ct]);
            }
        }
    }

#pragma unroll
    for (int r = 0; r < 4; ++r) {
        float inv = 1.f / lrow[r];
        size_t m = (size_t)(b * Nn + q0 + wv * 16 + kgrp * 4 + r);
#pragma unroll
        for (int ct = 0; ct < HD / 16; ++ct)
            Ob[m * Dd + h * HD + ct * 16 + rsel] = f2bf(oacc[ct][r] * inv);
    }
}

// ---------------- 3x3 weighted stencil on the 32x32 grid ----------------
__global__ __launch_bounds__(256) void stencil_kernel(
    const u16* __restrict__ xs, u16* __restrict__ nb)
{
    int tid = blockIdx.x * 256 + threadIdx.x;   // Mm*48 threads, 8 channels each
    if (tid >= Mm * 48) return;
    int c8 = tid % 48, pos = tid / 48;
    int j = pos & 31, i = (pos >> 5) & 31;
    float acc[8] = {0, 0, 0, 0, 0, 0, 0, 0};
    float wsum = 0.f;
#pragma unroll
    for (int di = -1; di <= 1; ++di) {
#pragma unroll
        for (int dj = -1; dj <= 1; ++dj) {
            int ii = i + di, jj = j + dj;
            if (ii < 0 || ii > 31 || jj < 0 || jj > 31) continue;
            float w = (di != 0 && dj != 0) ? 0.5f : 1.0f;
            uint4 vv = *(const uint4*)&xs[((size_t)pos + (size_t)(di * 32 + dj)) * Dd + c8 * 8];
            const u16* e = (const u16*)&vv;
#pragma unroll
            for (int q = 0; q < 8; ++q) acc[q] += w * bf2f(e[q]);
            wsum += w;
        }
    }
    float invw = 1.f / wsum;
    u16 ov[8];
#pragma unroll
    for (int q = 0; q < 8; ++q) ov[q] = f2bf(acc[q] * invw);
    *(uint4*)&nb[(size_t)pos * Dd + c8 * 8] = *(const uint4*)ov;
}

// ---------------- driver ----------------
extern "C" void kernel_launch(void* const* d_in, const int* in_sizes, int n_in,
                              void* d_out, int out_size, void* d_ws, size_t ws_size,
                              hipStream_t stream) {
    const float* x        = (const float*)d_in[0];
    const float* ln1_g    = (const float*)d_in[1];
    const float* ln1_b    = (const float*)d_in[2];
    const float* attn_wi  = (const float*)d_in[3];
    const float* attn_bi  = (const float*)d_in[4];
    const float* attn_wo  = (const float*)d_in[5];
    const float* attn_bo  = (const float*)d_in[6];
    const float* sln_g    = (const float*)d_in[7];
    const float* sln_b    = (const float*)d_in[8];
    const float* sattn_wi = (const float*)d_in[9];
    const float* sattn_bi = (const float*)d_in[10];
    const float* sattn_wo = (const float*)d_in[11];
    const float* sattn_bo = (const float*)d_in[12];
    const float* ln2_g    = (const float*)d_in[13];
    const float* ln2_b    = (const float*)d_in[14];
    const float* mlp_w1   = (const float*)d_in[15];
    const float* mlp_b1   = (const float*)d_in[16];
    const float* mlp_w2   = (const float*)d_in[17];
    const float* mlp_b2   = (const float*)d_in[18];
    float* out = (float*)d_out;

    char* base = (char*)d_ws;
    size_t off = 0;
    auto take = [&](size_t bytes) -> char* {
        char* p = base + off; off += (bytes + 255) & ~(size_t)255; return p;
    };
    u16* wbi1  = (u16*)take((size_t)1152 * 384 * 2);
    u16* wbo1  = (u16*)take((size_t)384 * 384 * 2);
    u16* wbi2  = (u16*)take((size_t)1152 * 384 * 2);
    u16* wbo2  = (u16*)take((size_t)384 * 384 * 2);
    u16* wbm1  = (u16*)take((size_t)MLPH * 384 * 2);
    u16* wbm2  = (u16*)take((size_t)384 * MLPH * 2);
    u16* bufA  = (u16*)take((size_t)Mm * Dd * 2);            // xn / xs / ln2
    u16* bufB  = (u16*)take((size_t)Mm * 1536 * 2);          // qkv1 | q2,kv2,nb | mlp hidden
    u16* bufO  = (u16*)take((size_t)Mm * Dd * 2);            // attention outputs
    u16* qkv1 = bufB;
    u16* q2   = bufB;
    u16* kv2  = bufB + (size_t)Mm * 384;
    u16* nbuf = bufB + (size_t)Mm * 1152;
    (void)ws_size; (void)in_sizes; (void)n_in; (void)out_size;

    // weights -> bf16
    cvt_kernel<<<(1152 * 384 + 255) / 256, 256, 0, stream>>>(attn_wi, wbi1, 1152 * 384);
    cvt_kernel<<<(384 * 384 + 255) / 256, 256, 0, stream>>>(attn_wo, wbo1, 384 * 384);
    cvt_kernel<<<(1152 * 384 + 255) / 256, 256, 0, stream>>>(sattn_wi, wbi2, 1152 * 384);
    cvt_kernel<<<(384 * 384 + 255) / 256, 256, 0, stream>>>(sattn_wo, wbo2, 384 * 384);
    cvt_kernel<<<(MLPH * 384 + 255) / 256, 256, 0, stream>>>(mlp_w1, wbm1, MLPH * 384);
    cvt_kernel<<<(384 * MLPH + 255) / 256, 256, 0, stream>>>(mlp_w2, wbm2, 384 * MLPH);

    // block 1: x = x + MHA(LN(x))
    ln_kernel<<<Mm / 4, 256, 0, stream>>>(x, ln1_g, ln1_b, bufA, out);
    gemm_bt<0><<<dim3(Mm / 128, 1152 / 128), 256, 0, stream>>>(
        bufA, Dd, wbi1, Dd, 0, attn_bi, 0, Dd, qkv1, 1152, nullptr, 1.f);
    attn_kernel<64><<<dim3(Nn / 64, H1, Bb), 256, 0, stream>>>(
        qkv1, 1152, qkv1 + Dd, 1152, qkv1 + 2 * Dd, 1152, bufO, 0.125f);
    gemm_bt<2><<<dim3(Mm / 128, Dd / 128), 256, 0, stream>>>(
        bufO, Dd, wbo1, Dd, 0, attn_bo, 0, Dd, out, Dd, out, 1.f);

    // block 2: x = x + 0.5 * MHA(xs, nb, nb)
    ln_kernel<<<Mm / 4, 256, 0, stream>>>(out, sln_g, sln_b, bufA, nullptr);
    stencil_kernel<<<(Mm * 48) / 256, 256, 0, stream>>>(bufA, nbuf);
    gemm_bt<0><<<dim3(Mm / 128, Dd / 128), 256, 0, stream>>>(
        bufA, Dd, wbi2, Dd, 0, sattn_bi, 0, Dd, q2, Dd, nullptr, 1.f);
    gemm_bt<0><<<dim3(Mm / 128, 768 / 128), 256, 0, stream>>>(
        nbuf, Dd, wbi2, Dd, 384, sattn_bi, 384, Dd, kv2, 768, nullptr, 1.f);
    attn_kernel<128><<<dim3(Nn / 64, H2, Bb), 256, 0, stream>>>(
        q2, Dd, kv2, 768, kv2 + Dd, 768, bufO, 0.088388347648318447f);
    gemm_bt<2><<<dim3(Mm / 128, Dd / 128), 256, 0, stream>>>(
        bufO, Dd, wbo2, Dd, 0, sattn_bo, 0, Dd, out, Dd, out, 0.5f);

    // MLP: x = x + W2 gelu(W1 LN(x))
    ln_kernel<<<Mm / 4, 256, 0, stream>>>(out, ln2_g, ln2_b, bufA, nullptr);
    gemm_bt<1><<<dim3(Mm / 128, MLPH / 128), 256, 0, stream>>>(
        bufA, Dd, wbm1, Dd, 0, mlp_b1, 0, Dd, bufB, MLPH, nullptr, 1.f);
    gemm_bt<2><<<dim3(Mm / 128, Dd / 128), 256, 0, stream>>>(
        bufB, MLPH, wbm2, MLPH, 0, mlp_b2, 0, MLPH, out, Dd, out, 1.f);
}

// Round 3
// 588.491 us; speedup vs baseline: 1.2166x; 1.0547x over previous
//
#include <hip/hip_runtime.h>
#include <math.h>

// SpatialTransformerBlock on MI355X (gfx950).
// Round 3: V stored pre-transposed in GEMM epilogue (kills 16-way scalar LDS
// transpose writes); XOR-swizzled (T2) LDS layouts in attention (unpadded,
// chunk ^= row&7 at 16B granularity) on both write and read.

typedef __attribute__((ext_vector_type(8))) short short8;   // 8 bf16 (4 VGPR) MFMA frag
typedef __attribute__((ext_vector_type(4))) float f32x4;    // MFMA accum
typedef unsigned short u16;

#define DEVI __device__ __forceinline__

static constexpr int Bb = 16, Nn = 1024, Dd = 384;
static constexpr int Mm = Bb * Nn;            // 16384 token rows
static constexpr int H1 = 6, HD1 = 64, H2 = 3, HD2 = 128, MLPH = 1536;

DEVI float bf2f(u16 u) { return __uint_as_float(((unsigned int)u) << 16); }
DEVI u16 f2bf(float f) {                       // round-nearest-even
    unsigned int x = __float_as_uint(f);
    return (u16)((x + 0x7fffu + ((x >> 16) & 1u)) >> 16);
}
DEVI f32x4 mfma16(short8 a, short8 b, f32x4 c) {
    return __builtin_amdgcn_mfma_f32_16x16x32_bf16(a, b, c, 0, 0, 0);
}

// ---------------- fp32 -> bf16 weight conversion ----------------
__global__ void cvt_kernel(const float* __restrict__ src, u16* __restrict__ dst, int n) {
    int i = blockIdx.x * 256 + threadIdx.x;
    if (i < n) dst[i] = f2bf(src[i]);
}

// ---------------- LayerNorm: 1 wave per 384-elem row ----------------
__global__ __launch_bounds__(256) void ln_kernel(
    const float* __restrict__ x, const float* __restrict__ g, const float* __restrict__ b,
    u16* __restrict__ out, float* __restrict__ xcopy)
{
    int wave = threadIdx.x >> 6, lane = threadIdx.x & 63;
    int row = blockIdx.x * 4 + wave;
    const float* xr = x + (size_t)row * Dd;
    float v[6], s = 0.f, sq = 0.f;
#pragma unroll
    for (int e = 0; e < 6; ++e) { v[e] = xr[e * 64 + lane]; s += v[e]; }
#pragma unroll
    for (int e = 0; e < 6; ++e) sq += v[e] * v[e];
#pragma unroll
    for (int m = 1; m < 64; m <<= 1) { s += __shfl_xor(s, m, 64); sq += __shfl_xor(sq, m, 64); }
    float mean = s * (1.f / 384.f);
    float var  = sq * (1.f / 384.f) - mean * mean;
    float rs   = rsqrtf(var + 1e-5f);
#pragma unroll
    for (int e = 0; e < 6; ++e) {
        int c = e * 64 + lane;
        out[(size_t)row * Dd + c] = f2bf((v[e] - mean) * rs * g[c] + b[c]);
        if (xcopy) xcopy[(size_t)row * Dd + c] = v[e];
    }
}

// ---------------- GEMM: C = A[M,K](bf16) @ W[wrow0+N, K](bf16)^T + bias ----------------
// 128x128 tile, 4 waves, 4x4 16x16x32 MFMAs per wave, BK=32.
// EPI: 0 = bias -> bf16 ; 1 = bias + exact GELU -> bf16 ; 2 = resid + alpha*(acc+bias) -> f32
// VT: columns n >= nvt0 are stored TRANSPOSED into vt[(n-nvt0)*Mm + m] (bf16).
template<int EPI, bool VT>
__global__ __launch_bounds__(256) void gemm_bt(
    const u16* __restrict__ A, int lda,
    const u16* __restrict__ W, int ldw, int wrow0,
    const float* __restrict__ bias, int brow0, int K,
    void* __restrict__ Cout, int ldc,
    const float* __restrict__ resid, float alpha,
    u16* __restrict__ vt, int nvt0)
{
    __shared__ __align__(16) u16 As[128][40];   // stride 80B: b128-floor pattern
    __shared__ __align__(16) u16 Bs[128][40];
    const int m0 = blockIdx.x * 128, n0 = blockIdx.y * 128;
    const int tid = threadIdx.x, wv = tid >> 6, lane = tid & 63;
    const int wr = wv >> 1, wc = wv & 1;
    const int rsel = lane & 15, ksel = (lane >> 4) * 8;

    f32x4 acc[4][4];
#pragma unroll
    for (int i = 0; i < 4; ++i)
#pragma unroll
        for (int j = 0; j < 4; ++j) acc[i][j] = f32x4{0.f, 0.f, 0.f, 0.f};

    for (int kb = 0; kb < K; kb += 32) {
        __syncthreads();
#pragma unroll
        for (int cc = 0; cc < 2; ++cc) {
            int c = tid + cc * 256;             // 512 16B chunks per 128x32 tile
            int r = c >> 2, cb = (c & 3) * 8;
            *(uint4*)&As[r][cb] = *(const uint4*)&A[(size_t)(m0 + r) * lda + kb + cb];
            *(uint4*)&Bs[r][cb] = *(const uint4*)&W[(size_t)(wrow0 + n0 + r) * ldw + kb + cb];
        }
        __syncthreads();
        short8 af[4], bfr[4];
#pragma unroll
        for (int i = 0; i < 4; ++i) af[i]  = *(const short8*)&As[wr * 64 + i * 16 + rsel][ksel];
#pragma unroll
        for (int j = 0; j < 4; ++j) bfr[j] = *(const short8*)&Bs[wc * 64 + j * 16 + rsel][ksel];
#pragma unroll
        for (int i = 0; i < 4; ++i)
#pragma unroll
            for (int j = 0; j < 4; ++j) acc[i][j] = mfma16(af[i], bfr[j], acc[i][j]);
    }

    const int rgrp4 = (lane >> 4) * 4, cidx = lane & 15;
#pragma unroll
    for (int i = 0; i < 4; ++i) {
        int mbase = m0 + wr * 64 + i * 16 + rgrp4;
#pragma unroll
        for (int j = 0; j < 4; ++j) {
            int n = n0 + wc * 64 + j * 16 + cidx;
            float bval = bias[brow0 + n];
            float vv[4];
#pragma unroll
            for (int r = 0; r < 4; ++r) vv[r] = acc[i][j][r] + bval;
            if constexpr (EPI == 0) {
                bool tv = false;
                if constexpr (VT) tv = (n >= nvt0);
                if (tv) {
                    u16 pk[4];
#pragma unroll
                    for (int r = 0; r < 4; ++r) pk[r] = f2bf(vv[r]);
                    *(uint2*)&vt[(size_t)(n - nvt0) * Mm + mbase] = *(const uint2*)pk;
                } else {
#pragma unroll
                    for (int r = 0; r < 4; ++r)
                        ((u16*)Cout)[(size_t)(mbase + r) * ldc + n] = f2bf(vv[r]);
                }
            } else if constexpr (EPI == 1) {
#pragma unroll
                for (int r = 0; r < 4; ++r) {
                    float gg = 0.5f * vv[r] * (1.f + erff(vv[r] * 0.70710678118654752f));
                    ((u16*)Cout)[(size_t)(mbase + r) * ldc + n] = f2bf(gg);
                }
            } else {
#pragma unroll
                for (int r = 0; r < 4; ++r)
                    ((float*)Cout)[(size_t)(mbase + r) * ldc + n] =
                        resid[(size_t)(mbase + r) * ldc + n] + alpha * vv[r];
            }
        }
    }
}

// ---------------- fused attention (flash-style, online softmax) ----------------
// Block: 4 waves, 64 Q-rows (16 per wave). 16 KV tiles of 64.
// V comes pre-transposed from global: VTb[(h*HD+d)*Mm + b*Nn + kv].
// All LDS tiles XOR-swizzled: 16B-chunk index ^= (row & 7).
template<int HD>
__global__ __launch_bounds__(256) void attn_kernel(
    const u16* __restrict__ Qb, int qs,
    const u16* __restrict__ Kb, int ks,
    const u16* __restrict__ VTb,
    u16* __restrict__ Ob, float scale)
{
    constexpr int CH = HD / 8;                  // 16B chunks per row
    __shared__ __align__(16) u16 Qs[64][HD];
    __shared__ __align__(16) u16 Ks[64][HD];
    __shared__ __align__(16) u16 Vs[HD][64];    // [d][kv], swizzled
    __shared__ __align__(16) u16 Ps[4][16][64]; // per-wave P strip, swizzled

    const int q0 = blockIdx.x * 64, h = blockIdx.y, b = blockIdx.z;
    const int tid = threadIdx.x, wv = tid >> 6, lane = tid & 63;
    const int rsel = lane & 15, kgrp = lane >> 4;

    for (int c = tid; c < 64 * CH; c += 256) {
        int r = c / CH, ch = c % CH, chs = ch ^ (r & 7);
        *(uint4*)&Qs[r][chs * 8] =
            *(const uint4*)&Qb[(size_t)(b * Nn + q0 + r) * qs + h * HD + ch * 8];
    }

    float mrow[4], lrow[4];
    f32x4 oacc[HD / 16];
#pragma unroll
    for (int r = 0; r < 4; ++r) { mrow[r] = -INFINITY; lrow[r] = 0.f; }
#pragma unroll
    for (int ct = 0; ct < HD / 16; ++ct) oacc[ct] = f32x4{0.f, 0.f, 0.f, 0.f};

    for (int t = 0; t < Nn / 64; ++t) {
        int kv0 = t * 64;
        __syncthreads();                        // prev-iter LDS reads done
        for (int c = tid; c < 64 * CH; c += 256) {
            int r = c / CH, ch = c % CH, chs = ch ^ (r & 7);
            *(uint4*)&Ks[r][chs * 8] =
                *(const uint4*)&Kb[(size_t)(b * Nn + kv0 + r) * ks + h * HD + ch * 8];
        }
        for (int c = tid; c < HD * 8; c += 256) {
            int d = c >> 3, ch = c & 7, chs = ch ^ (d & 7);
            *(uint4*)&Vs[d][chs * 8] =
                *(const uint4*)&VTb[(size_t)(h * HD + d) * Mm + b * Nn + kv0 + ch * 8];
        }
        __syncthreads();

        // S = Q K^T  (wave's 16-row strip x 64 kv)
        f32x4 sacc[4];
#pragma unroll
        for (int ct = 0; ct < 4; ++ct) sacc[ct] = f32x4{0.f, 0.f, 0.f, 0.f};
#pragma unroll
        for (int kk = 0; kk < HD / 32; ++kk) {
            int qrow = wv * 16 + rsel;
            short8 aq = *(const short8*)&Qs[qrow][((4 * kk + kgrp) ^ (qrow & 7)) * 8];
#pragma unroll
            for (int ct = 0; ct < 4; ++ct) {
                int krow = ct * 16 + rsel;
                short8 bk = *(const short8*)&Ks[krow][((4 * kk + kgrp) ^ (krow & 7)) * 8];
                sacc[ct] = mfma16(aq, bk, sacc[ct]);
            }
        }
        // online softmax; D layout: row = 4*kgrp+r, col = ct*16+rsel
#pragma unroll
        for (int r = 0; r < 4; ++r) {
            float s0 = sacc[0][r] * scale, s1 = sacc[1][r] * scale;
            float s2 = sacc[2][r] * scale, s3 = sacc[3][r] * scale;
            float mx = fmaxf(fmaxf(s0, s1), fmaxf(s2, s3));
#pragma unroll
            for (int mk = 1; mk < 16; mk <<= 1) mx = fmaxf(mx, __shfl_xor(mx, mk, 64));
            float mnew = fmaxf(mrow[r], mx);
            float al = __expf(mrow[r] - mnew);
            float p0 = __expf(s0 - mnew), p1 = __expf(s1 - mnew);
            float p2 = __expf(s2 - mnew), p3 = __expf(s3 - mnew);
            float rsum = p0 + p1 + p2 + p3;
#pragma unroll
            for (int mk = 1; mk < 16; mk <<= 1) rsum += __shfl_xor(rsum, mk, 64);
            lrow[r] = lrow[r] * al + rsum;
            mrow[r] = mnew;
#pragma unroll
            for (int ct = 0; ct < HD / 16; ++ct) oacc[ct][r] *= al;
            int prow = kgrp * 4 + r;
            float pv[4] = {p0, p1, p2, p3};
#pragma unroll
            for (int ct = 0; ct < 4; ++ct) {
                int chs = ((2 * ct + (rsel >> 3)) ^ (prow & 7));
                Ps[wv][prow][chs * 8 + (rsel & 7)] = f2bf(pv[ct]);
            }
        }
        __syncthreads();                        // P visible (and K/V staged)

        // O += P V
#pragma unroll
        for (int kk = 0; kk < 2; ++kk) {
            short8 ap = *(const short8*)&Ps[wv][rsel][((4 * kk + kgrp) ^ (rsel & 7)) * 8];
#pragma unroll
            for (int ct = 0; ct < HD / 16; ++ct) {
                int vrow = ct * 16 + rsel;
                short8 bv = *(const short8*)&Vs[vrow][((4 * kk + kgrp) ^ (vrow & 7)) * 8];
                oacc[ct] = mfma16(ap, bv, oacc[ct]);
            }
        }
    }

#pragma unroll
    for (int r = 0; r < 4; ++r) {
        float inv = 1.f / lrow[r];
        size_t m = (size_t)(b * Nn + q0 + wv * 16 + kgrp * 4 + r);
#pragma unroll
        for (int ct = 0; ct < HD / 16; ++ct)
            Ob[m * Dd + h * HD + ct * 16 + rsel] = f2bf(oacc[ct][r] * inv);
    }
}

// ---------------- 3x3 weighted stencil on the 32x32 grid ----------------
__global__ __launch_bounds__(256) void stencil_kernel(
    const u16* __restrict__ xs, u16* __restrict__ nb)
{
    int tid = blockIdx.x * 256 + threadIdx.x;   // Mm*48 threads, 8 channels each
    if (tid >= Mm * 48) return;
    int c8 = tid % 48, pos = tid / 48;
    int j = pos & 31, i = (pos >> 5) & 31;
    float acc[8] = {0, 0, 0, 0, 0, 0, 0, 0};
    float wsum = 0.f;
#pragma unroll
    for (int di = -1; di <= 1; ++di) {
#pragma unroll
        for (int dj = -1; dj <= 1; ++dj) {
            int ii = i + di, jj = j + dj;
            if (ii < 0 || ii > 31 || jj < 0 || jj > 31) continue;
            float w = (di != 0 && dj != 0) ? 0.5f : 1.0f;
            uint4 vv = *(const uint4*)&xs[((size_t)pos + (size_t)(di * 32 + dj)) * Dd + c8 * 8];
            const u16* e = (const u16*)&vv;
#pragma unroll
            for (int q = 0; q < 8; ++q) acc[q] += w * bf2f(e[q]);
            wsum += w;
        }
    }
    float invw = 1.f / wsum;
    u16 ov[8];
#pragma unroll
    for (int q = 0; q < 8; ++q) ov[q] = f2bf(acc[q] * invw);
    *(uint4*)&nb[(size_t)pos * Dd + c8 * 8] = *(const uint4*)ov;
}

// ---------------- driver ----------------
extern "C" void kernel_launch(void* const* d_in, const int* in_sizes, int n_in,
                              void* d_out, int out_size, void* d_ws, size_t ws_size,
                              hipStream_t stream) {
    const float* x        = (const float*)d_in[0];
    const float* ln1_g    = (const float*)d_in[1];
    const float* ln1_b    = (const float*)d_in[2];
    const float* attn_wi  = (const float*)d_in[3];
    const float* attn_bi  = (const float*)d_in[4];
    const float* attn_wo  = (const float*)d_in[5];
    const float* attn_bo  = (const float*)d_in[6];
    const float* sln_g    = (const float*)d_in[7];
    const float* sln_b    = (const float*)d_in[8];
    const float* sattn_wi = (const float*)d_in[9];
    const float* sattn_bi = (const float*)d_in[10];
    const float* sattn_wo = (const float*)d_in[11];
    const float* sattn_bo = (const float*)d_in[12];
    const float* ln2_g    = (const float*)d_in[13];
    const float* ln2_b    = (const float*)d_in[14];
    const float* mlp_w1   = (const float*)d_in[15];
    const float* mlp_b1   = (const float*)d_in[16];
    const float* mlp_w2   = (const float*)d_in[17];
    const float* mlp_b2   = (const float*)d_in[18];
    float* out = (float*)d_out;

    char* base = (char*)d_ws;
    size_t off = 0;
    auto take = [&](size_t bytes) -> char* {
        char* p = base + off; off += (bytes + 255) & ~(size_t)255; return p;
    };
    u16* wbi1  = (u16*)take((size_t)1152 * 384 * 2);
    u16* wbo1  = (u16*)take((size_t)384 * 384 * 2);
    u16* wbi2  = (u16*)take((size_t)1152 * 384 * 2);
    u16* wbo2  = (u16*)take((size_t)384 * 384 * 2);
    u16* wbm1  = (u16*)take((size_t)MLPH * 384 * 2);
    u16* wbm2  = (u16*)take((size_t)384 * MLPH * 2);
    u16* bufA  = (u16*)take((size_t)Mm * Dd * 2);            // xn / xs / ln2
    u16* bufB  = (u16*)take((size_t)Mm * 1536 * 2);          // see layout below
    u16* bufO  = (u16*)take((size_t)Mm * Dd * 2);            // attention outputs
    // bufB layout, phase 1: [ Q1 K1 | Vt1 ] :  Q/K at cols 0..767 (ldc 768), Vt1 at +Mm*768
    // bufB layout, phase 2: [ q2 | k2 | vt2 | nbuf ]  each Mm*384
    // bufB layout, phase 3: mlp hidden (Mm*1536)
    u16* qkv1 = bufB;
    u16* vt1  = bufB + (size_t)Mm * 768;
    u16* q2   = bufB;
    u16* k2   = bufB + (size_t)Mm * 384;
    u16* vt2  = bufB + (size_t)Mm * 768;
    u16* nbuf = bufB + (size_t)Mm * 1152;
    (void)ws_size; (void)in_sizes; (void)n_in; (void)out_size;

    // weights -> bf16
    cvt_kernel<<<(1152 * 384 + 255) / 256, 256, 0, stream>>>(attn_wi, wbi1, 1152 * 384);
    cvt_kernel<<<(384 * 384 + 255) / 256, 256, 0, stream>>>(attn_wo, wbo1, 384 * 384);
    cvt_kernel<<<(1152 * 384 + 255) / 256, 256, 0, stream>>>(sattn_wi, wbi2, 1152 * 384);
    cvt_kernel<<<(384 * 384 + 255) / 256, 256, 0, stream>>>(sattn_wo, wbo2, 384 * 384);
    cvt_kernel<<<(MLPH * 384 + 255) / 256, 256, 0, stream>>>(mlp_w1, wbm1, MLPH * 384);
    cvt_kernel<<<(384 * MLPH + 255) / 256, 256, 0, stream>>>(mlp_w2, wbm2, 384 * MLPH);

    // block 1: x = x + MHA(LN(x));  QKV GEMM writes Q,K normal (ldc 768), V transposed
    ln_kernel<<<Mm / 4, 256, 0, stream>>>(x, ln1_g, ln1_b, bufA, out);
    gemm_bt<0, true><<<dim3(Mm / 128, 1152 / 128), 256, 0, stream>>>(
        bufA, Dd, wbi1, Dd, 0, attn_bi, 0, Dd, qkv1, 768, nullptr, 1.f, vt1, 768);
    attn_kernel<64><<<dim3(Nn / 64, H1, Bb), 256, 0, stream>>>(
        qkv1, 768, qkv1 + 384, 768, vt1, bufO, 0.125f);
    gemm_bt<2, false><<<dim3(Mm / 128, Dd / 128), 256, 0, stream>>>(
        bufO, Dd, wbo1, Dd, 0, attn_bo, 0, Dd, out, Dd, out, 1.f, nullptr, 0);

    // block 2: x = x + 0.5 * MHA(xs, nb, nb)
    ln_kernel<<<Mm / 4, 256, 0, stream>>>(out, sln_g, sln_b, bufA, nullptr);
    stencil_kernel<<<(Mm * 48) / 256, 256, 0, stream>>>(bufA, nbuf);
    gemm_bt<0, false><<<dim3(Mm / 128, Dd / 128), 256, 0, stream>>>(
        bufA, Dd, wbi2, Dd, 0, sattn_bi, 0, Dd, q2, Dd, nullptr, 1.f, nullptr, 0);
    gemm_bt<0, true><<<dim3(Mm / 128, 768 / 128), 256, 0, stream>>>(
        nbuf, Dd, wbi2, Dd, 384, sattn_bi, 384, Dd, k2, 384, nullptr, 1.f, vt2, 384);
    attn_kernel<128><<<dim3(Nn / 64, H2, Bb), 256, 0, stream>>>(
        q2, 384, k2, 384, vt2, bufO, 0.088388347648318447f);
    gemm_bt<2, false><<<dim3(Mm / 128, Dd / 128), 256, 0, stream>>>(
        bufO, Dd, wbo2, Dd, 0, sattn_bo, 0, Dd, out, Dd, out, 0.5f, nullptr, 0);

    // MLP: x = x + W2 gelu(W1 LN(x))
    ln_kernel<<<Mm / 4, 256, 0, stream>>>(out, ln2_g, ln2_b, bufA, nullptr);
    gemm_bt<1, false><<<dim3(Mm / 128, MLPH / 128), 256, 0, stream>>>(
        bufA, Dd, wbm1, Dd, 0, mlp_b1, 0, Dd, bufB, MLPH, nullptr, 1.f, nullptr, 0);
    gemm_bt<2, false><<<dim3(Mm / 128, Dd / 128), 256, 0, stream>>>(
        bufB, MLPH, wbm2, MLPH, 0, mlp_b2, 0, MLPH, out, Dd, out, 1.f, nullptr, 0);
}